// Round 3
// baseline (993.863 us; speedup 1.0000x reference)
//
#include <hip/hip_runtime.h>
#include <hip/hip_bf16.h>

typedef unsigned short u16;

#define Bb 2
#define Ll 8192
#define Dd 1024
#define Hh 16
#define Pp 64
#define CLc 256
#define NCc 32
#define Mm 16384   // B*L
#define DD2 ((size_t)Dd*Dd)

typedef __attribute__((ext_vector_type(8))) short short8b;   // 8 bf16 (4 VGPRs)
typedef __attribute__((ext_vector_type(4))) float f32x4v;    // MFMA C/D

__device__ __forceinline__ float bf2f(u16 u){
    return __uint_as_float(((unsigned int)u) << 16);
}
__device__ __forceinline__ u16 f2bf(float f){
    unsigned int i = __float_as_uint(f);
    unsigned int r = (i + 0x7FFFu + ((i >> 16) & 1u)) >> 16;  // RNE
    return (u16)r;
}

// DT: 1 = bf16, 0 = fp32
template<int DT>
__device__ __forceinline__ float ld1(const void* p, size_t i){
    return DT ? bf2f(((const u16*)p)[i]) : ((const float*)p)[i];
}
template<int DT>
__device__ __forceinline__ void ld8(const void* p, size_t i, float* o){
    if (DT){
        const u16* q = (const u16*)p + i;
        ushort4 a0 = *(const ushort4*)q;
        ushort4 a1 = *(const ushort4*)(q + 4);
        o[0]=bf2f(a0.x); o[1]=bf2f(a0.y); o[2]=bf2f(a0.z); o[3]=bf2f(a0.w);
        o[4]=bf2f(a1.x); o[5]=bf2f(a1.y); o[6]=bf2f(a1.z); o[7]=bf2f(a1.w);
    } else {
        const float* q = (const float*)p + i;
        float4 a0 = *(const float4*)q;
        float4 a1 = *(const float4*)(q + 4);
        o[0]=a0.x; o[1]=a0.y; o[2]=a0.z; o[3]=a0.w;
        o[4]=a1.x; o[5]=a1.y; o[6]=a1.z; o[7]=a1.w;
    }
}

// async global->LDS, 16B per lane; LDS dest must be wave-uniform base (+lane*16 by HW)
typedef __attribute__((address_space(3))) void lds_t;
typedef __attribute__((address_space(1))) const void gm_t;
__device__ __forceinline__ void gload16(const void* g, void* l){
    __builtin_amdgcn_global_load_lds((gm_t*)g, (lds_t*)l, 16, 0, 0);
}

// ---------------------------------------------------------------------------
// Dtype sniff: cos[0] row is 1.0f. fp32 -> 0x3F800000; bf16 -> 0x3F803F80.
// ---------------------------------------------------------------------------
__global__ void sniff_kernel(const unsigned int* __restrict__ cosw, int* __restrict__ flag){
    if (threadIdx.x == 0 && blockIdx.x == 0)
        *flag = (cosw[0] == 0x3F800000u) ? 0 : 1;
}

// ---------------------------------------------------------------------------
// hs -> bf16 workspace copy/convert (gated on dtype).
// ---------------------------------------------------------------------------
template<int DT>
__global__ __launch_bounds__(256) void cvt_kernel(
    const void* __restrict__ in, u16* __restrict__ out, const int* __restrict__ flag)
{
    if (*flag != DT) return;
    size_t i = ((size_t)blockIdx.x*256 + threadIdx.x) * 8;
    float v[8]; ld8<DT>(in, i, v);
    ushort4 o0, o1;
    o0.x=f2bf(v[0]); o0.y=f2bf(v[1]); o0.z=f2bf(v[2]); o0.w=f2bf(v[3]);
    o1.x=f2bf(v[4]); o1.y=f2bf(v[5]); o1.z=f2bf(v[6]); o1.w=f2bf(v[7]);
    *(ushort4*)(out + i)     = o0;
    *(ushort4*)(out + i + 4) = o1;
}

// ---------------------------------------------------------------------------
// Transpose-convert 1024x1024 weights to bf16 W^T (N-major, k-contiguous).
// z selects {Wc,Wb,Wx,Wout}. For Wout (z==3) also emit the bf16x2 low part
// (Wlo = W - bf16(W)) so the fp32-mode output GEMM keeps ~fp32 W precision.
// ---------------------------------------------------------------------------
template<int DT>
__global__ __launch_bounds__(256) void wtrans_kernel(
    const void* __restrict__ W0, const void* __restrict__ W1,
    const void* __restrict__ W2, const void* __restrict__ W3,
    u16* __restrict__ out, const int* __restrict__ flag)
{
    if (*flag != DT) return;
    const int z = blockIdx.z;
    const void* W = (z==0) ? W0 : (z==1) ? W1 : (z==2) ? W2 : W3;
    u16* Whi = out + (size_t)z*DD2;
    u16* Wlo = out + (size_t)4*DD2;
    __shared__ u16 th[64][65];
    __shared__ u16 tlo[64][65];
    const int t = threadIdx.x;
    const int r = t >> 2, cq = (t & 3)*16;
    size_t base = ((size_t)blockIdx.y*64 + r)*1024 + (size_t)blockIdx.x*64 + cq;
    float v[8];
#pragma unroll
    for (int half = 0; half < 2; half++){
        ld8<DT>(W, base + half*8, v);
#pragma unroll
        for (int j = 0; j < 8; j++){
            u16 hi = f2bf(v[j]);
            th[r][cq + half*8 + j]  = hi;
            tlo[r][cq + half*8 + j] = f2bf(v[j] - bf2f(hi));
        }
    }
    __syncthreads();
    size_t ob = ((size_t)blockIdx.x*64 + r)*1024 + (size_t)blockIdx.y*64 + cq;
#pragma unroll
    for (int j = 0; j < 16; j++)
        Whi[ob + j] = th[cq + j][r];
    if (z == 3){
#pragma unroll
        for (int j = 0; j < 16; j++)
            Wlo[ob + j] = tlo[cq + j][r];
    }
}

// ---------------------------------------------------------------------------
// bf16 MFMA GEMM: C[M,N] = A[M,K] @ Bt[N,K]^T  (Bt is the transposed weight).
// m97 structure: 4 waves, 128x128 tile, BK=32, global_load_lds width 16,
// 8 ds_read_b128 + 16 v_mfma_f32_16x16x32_bf16 per K-step.
// DTC: 1 -> bf16 C, 0 -> fp32 C.  ACC: 1 -> C += (fp32 only).
// want: -1 ungated, else require *flag == want.
// ---------------------------------------------------------------------------
template<int DTC, int ACC>
__global__ __launch_bounds__(256) void gemm_mfma(
    const u16* __restrict__ A, const u16* __restrict__ Bt, void* __restrict__ C,
    int M, int N, int K, const int* __restrict__ flag, int want)
{
    if (want >= 0 && *flag != want) return;
    __shared__ __align__(128) u16 As[128*32];   // 8 KB, [row][k]
    __shared__ __align__(128) u16 Bs[128*32];   // 8 KB, [col][k]
    const int t    = threadIdx.x;
    const int wave = t >> 6;
    const int lane = t & 63;

    // XCD-aware bijective block swizzle (grid % 8 == 0 for all our shapes)
    const int nbn = N >> 7;
    int wg = blockIdx.x, nwg = gridDim.x, swz = wg;
    if ((nwg & 7) == 0){
        int cpx = nwg >> 3;
        swz = (wg & 7)*cpx + (wg >> 3);
    }
    const int bm = swz / nbn, bn = swz % nbn;

    // staging: each wave's gload covers 16 rows (64 lanes x 16B = 1024B)
    const int ldrow = wave*16 + (lane >> 2);   // 0..63
    const int ldk   = (lane & 3)*8;            // element offset in k
    const u16* Ag0 = A  + (size_t)(bm*128 + ldrow)*K + ldk;
    const u16* Ag1 = Ag0 + (size_t)64*K;
    const u16* Bg0 = Bt + (size_t)(bn*128 + ldrow)*K + ldk;
    const u16* Bg1 = Bg0 + (size_t)64*K;
    u16* AsD0 = &As[(wave*16)*32];             // wave-uniform LDS bases
    u16* AsD1 = &As[(64 + wave*16)*32];
    u16* BsD0 = &Bs[(wave*16)*32];
    u16* BsD1 = &Bs[(64 + wave*16)*32];

    // compute: wave (wr,wc) owns a 64x64 sub-tile
    const int wr = wave >> 1, wc = wave & 1;
    const int fr = lane & 15;                  // fragment row/col
    const int fk = (lane >> 4)*8;              // fragment k base
    const u16* a_rd = &As[(wr*64 + fr)*32 + fk];
    const u16* b_rd = &Bs[(wc*64 + fr)*32 + fk];

    f32x4v acc[4][4] = {};

    for (int k0 = 0; k0 < K; k0 += 32){
        gload16(Ag0 + k0, AsD0);
        gload16(Ag1 + k0, AsD1);
        gload16(Bg0 + k0, BsD0);
        gload16(Bg1 + k0, BsD1);
        __syncthreads();                       // drains vmcnt(0) before barrier
        short8b af[4], bf[4];
#pragma unroll
        for (int i = 0; i < 4; i++){
            af[i] = *(const short8b*)(a_rd + i*16*32);
            bf[i] = *(const short8b*)(b_rd + i*16*32);
        }
#pragma unroll
        for (int mi = 0; mi < 4; mi++)
#pragma unroll
            for (int ni = 0; ni < 4; ni++)
                acc[mi][ni] = __builtin_amdgcn_mfma_f32_16x16x32_bf16(
                    af[mi], bf[ni], acc[mi][ni], 0, 0, 0);
        __syncthreads();                       // LDS reads done before next stage
    }

    // epilogue: C/D layout col=lane&15, row=(lane>>4)*4+reg  [verified]
    const int crow = (lane >> 4)*4;
    const int ccol = lane & 15;
#pragma unroll
    for (int mi = 0; mi < 4; mi++){
#pragma unroll
        for (int ni = 0; ni < 4; ni++){
            size_t col = (size_t)bn*128 + wc*64 + ni*16 + ccol;
#pragma unroll
            for (int r = 0; r < 4; r++){
                size_t row = (size_t)bm*128 + wr*64 + mi*16 + crow + r;
                float v = acc[mi][ni][r];
                if (DTC){
                    ((u16*)C)[row*(size_t)N + col] = f2bf(v);
                } else {
                    float* p = (float*)C + row*(size_t)N + col;
                    *p = ACC ? (*p + v) : v;
                }
            }
        }
    }
}

// ---------------------------------------------------------------------------
// dt = softplus(hs @ Wdt)  (M x 16, K=1024).  16 tokens per block.
// ---------------------------------------------------------------------------
template<int DT>
__global__ __launch_bounds__(256) void dt_kernel(
    const void* __restrict__ hs, const void* __restrict__ Wdt,
    float* __restrict__ dtb, const int* __restrict__ flag)
{
    if (*flag != DT) return;
    __shared__ u16 hss[16*1024];   // 32 KB
    __shared__ u16 wds[1024*16];   // 32 KB
    const int t = threadIdx.x;
    const size_t tok0 = (size_t)blockIdx.x * 16;
    float v[8];
#pragma unroll
    for (int i = 0; i < 8; i++){
        size_t e = (size_t)i*2048 + (size_t)t*8;
        ld8<DT>(hs, tok0*1024 + e, v);
#pragma unroll
        for (int j=0;j<8;j++) hss[e+j] = f2bf(v[j]);
        ld8<DT>(Wdt, e, v);
#pragma unroll
        for (int j=0;j<8;j++) wds[e+j] = f2bf(v[j]);
    }
    __syncthreads();
    const int token = t >> 4, h = t & 15;
    float accv = 0.f;
    for (int k = 0; k < 1024; k++)
        accv += bf2f(hss[token*1024+k]) * bf2f(wds[k*16+h]);
    float sp = (accv > 20.f) ? accv : log1pf(__expf(accv));
    dtb[(tok0 + token)*16 + h] = sp;
}

// ---------------------------------------------------------------------------
// RoPE on c and b (in place, ws bf16) + xdt = x * dt (in place on x buffer).
// ---------------------------------------------------------------------------
template<int DT>
__global__ __launch_bounds__(256) void rope_xdt_kernel(
    u16* cb, u16* bb, u16* xb, const float* __restrict__ dtb,
    const void* __restrict__ cosb, const void* __restrict__ sinb,
    const int* __restrict__ flag)
{
    if (*flag != DT) return;
    const int t = blockIdx.x*256 + threadIdx.x;       // [0, M*H*32)
    const int p = t & 31, h = (t >> 5) & 15;
    const size_t token = (size_t)(t >> 9);
    const size_t base = token*Dd + h*Pp;
    const float cs0 = ld1<DT>(cosb, token*64 + p);
    const float cs1 = ld1<DT>(cosb, token*64 + p + 32);
    const float sn0 = ld1<DT>(sinb, token*64 + p);
    const float sn1 = ld1<DT>(sinb, token*64 + p + 32);
    float c0 = bf2f(cb[base+p]), c1 = bf2f(cb[base+p+32]);
    cb[base+p]    = f2bf(c0*cs0 - c1*sn0);
    cb[base+p+32] = f2bf(c1*cs1 + c0*sn1);
    float b0 = bf2f(bb[base+p]), b1 = bf2f(bb[base+p+32]);
    bb[base+p]    = f2bf(b0*cs0 - b1*sn0);
    bb[base+p+32] = f2bf(b1*cs1 + b0*sn1);
    const float dv = dtb[token*Hh + h];
    xb[base+p]    = f2bf(bf2f(xb[base+p]) * dv);
    xb[base+p+32] = f2bf(bf2f(xb[base+p+32]) * dv);
}

// ---------------------------------------------------------------------------
// Acum[b][h][c][l] = inclusive cumsum over l of dt[token][h]*A[h] per chunk.
// ---------------------------------------------------------------------------
template<int DT>
__global__ __launch_bounds__(256) void cumsum_kernel(
    const float* __restrict__ dtb, const void* __restrict__ Aarr,
    float* __restrict__ Acum, const int* __restrict__ flag)
{
    if (*flag != DT) return;
    const int g = blockIdx.x;
    const int c = g & 31, h = (g >> 5) & 15, b = g >> 9;
    const int l = threadIdx.x;
    __shared__ float s[256];
    const size_t token = (size_t)b*Ll + (size_t)c*CLc + l;
    s[l] = dtb[token*Hh + h] * ld1<DT>(Aarr, h);
    __syncthreads();
    for (int off = 1; off < 256; off <<= 1){
        float add = (l >= off) ? s[l - off] : 0.f;
        __syncthreads();
        s[l] += add;
        __syncthreads();
    }
    Acum[((size_t)(b*Hh + h)*NCc + c)*CLc + l] = s[l];
}

// ---------------------------------------------------------------------------
// Per (b, chunk, h): phase 1 states[p][n], phase 2 Y_diag rows.
// f32 LDS staging; phase 2 is WAVE-UNIFORM in s (each wave walks s from its
// top row downward; lanes keep their own l; s>l lanes masked to 0).
// All brs/xds reads in the hot loops are same-address broadcasts -> zero
// bank conflicts.
// FIX (r2->r3): the wave-uniform exit must use the wave's MAX Acum
// (acs[wv*64], first row of the wave's range; Acum is non-increasing), not
// the min -- exiting on the min dropped live terms for low-l lanes.
// ---------------------------------------------------------------------------
__global__ __launch_bounds__(256) void chunk_kernel(
    const u16* __restrict__ cr, u16* brY, const u16* __restrict__ xd,
    const float* __restrict__ Acum, float* __restrict__ states)
{
    __shared__ float brs[256*64];   // 64 KB f32
    __shared__ float xds[256*64];   // 64 KB f32
    __shared__ float acs[256];      // 1 KB
    const int g = blockIdx.x;
    const int h = g & 15, c = (g >> 4) & 31, b = g >> 9;
    const int t = threadIdx.x;
    const size_t tokbase = (size_t)b*Ll + (size_t)c*CLc;
    const float* Ac = Acum + ((size_t)(b*Hh + h)*NCc + c)*CLc;
    acs[t] = Ac[t];
#pragma unroll
    for (int i = 0; i < 8; i++){
        int f8 = i*256 + t;           // 0..2047
        int l  = f8 >> 3;             // row 0..255
        int n8 = (f8 & 7) * 8;        // 0,8,..,56
        size_t goff = (tokbase + l)*Dd + h*Pp + n8;
        ushort4 a0 = *(const ushort4*)&brY[goff];
        ushort4 a1 = *(const ushort4*)&brY[goff + 4];
        float* d1p = &brs[l*64 + n8];
        d1p[0]=bf2f(a0.x); d1p[1]=bf2f(a0.y); d1p[2]=bf2f(a0.z); d1p[3]=bf2f(a0.w);
        d1p[4]=bf2f(a1.x); d1p[5]=bf2f(a1.y); d1p[6]=bf2f(a1.z); d1p[7]=bf2f(a1.w);
        ushort4 b0 = *(const ushort4*)&xd[goff];
        ushort4 b1 = *(const ushort4*)&xd[goff + 4];
        float* d2p = &xds[l*64 + n8];
        d2p[0]=bf2f(b0.x); d2p[1]=bf2f(b0.y); d2p[2]=bf2f(b0.z); d2p[3]=bf2f(b0.w);
        d2p[4]=bf2f(b1.x); d2p[5]=bf2f(b1.y); d2p[6]=bf2f(b1.z); d2p[7]=bf2f(b1.w);
    }
    __syncthreads();

    // phase 1: states[p][n] = sum_l exp(a_last - a_l) * xdt[l][p] * br[l][n]
    {
        const int n  = t & 63;
        const int pb = (t >> 6) * 16;
        const float a_last = acs[255];
        // first live l (monotone: qualifying set is a suffix)
        int l0 = 0;
#pragma unroll
        for (int j = 0; j < 4; j++){
            unsigned long long m = __ballot(a_last - acs[j*64 + (t & 63)] >= -30.f);
            if (m){ l0 = j*64 + (__ffsll((unsigned long long)m) - 1); break; }
        }
        float4 f4a[4];
#pragma unroll
        for (int q = 0; q < 4; q++) f4a[q] = make_float4(0.f,0.f,0.f,0.f);
        for (int l = l0; l < 256; l++){
            float w  = __expf(fminf(a_last - acs[l], 0.f));
            float bv = w * brs[l*64 + n];
            const float4* xrow = (const float4*)&xds[l*64 + pb];
#pragma unroll
            for (int q = 0; q < 4; q++){
                float4 xv = xrow[q];
                f4a[q].x += bv*xv.x; f4a[q].y += bv*xv.y;
                f4a[q].z += bv*xv.z; f4a[q].w += bv*xv.w;
            }
        }
        float* st = states + ((size_t)((b*NCc + c)*Hh) + h)*4096;
#pragma unroll
        for (int q = 0; q < 4; q++){
            st[(pb + 4*q + 0)*64 + n] = f4a[q].x;
            st[(pb + 4*q + 1)*64 + n] = f4a[q].y;
            st[(pb + 4*q + 2)*64 + n] = f4a[q].z;
            st[(pb + 4*q + 3)*64 + n] = f4a[q].w;
        }
    }

    // phase 2: Y_diag[l][p] = sum_{s<=l} exp(a_l-a_s) * (cr[l].br[s]) * xdt[s][p]
    // wave-uniform s loop: broadcast LDS reads, uniform break on wave-MAX Acum.
    {
        const int wv = t >> 6;
        const int l  = t;
        const float a_l = acs[l];
        float4 cr4[16];
        {
            const u16* crp = cr + (tokbase + l)*Dd + h*Pp;
#pragma unroll
            for (int q = 0; q < 8; q++){
                ushort4 u0 = *(const ushort4*)(crp + q*8);
                ushort4 u1 = *(const ushort4*)(crp + q*8 + 4);
                cr4[2*q]   = make_float4(bf2f(u0.x), bf2f(u0.y), bf2f(u0.z), bf2f(u0.w));
                cr4[2*q+1] = make_float4(bf2f(u1.x), bf2f(u1.y), bf2f(u1.z), bf2f(u1.w));
            }
        }
        float4 acc4[16];
#pragma unroll
        for (int q = 0; q < 16; q++) acc4[q] = make_float4(0.f,0.f,0.f,0.f);
        const float a_hi = acs[wv*64];            // wave's MAX Acum (row 0 of range)
        for (int s = wv*64 + 63; s >= 0; --s){
            const float a_s = acs[s];
            if (a_hi - a_s < -30.f) break;        // all lanes' weights < e^-30
            const float4* brow = (const float4*)&brs[s*64];
            float dp0=0.f,dp1=0.f,dp2=0.f,dp3=0.f,dp4=0.f,dp5=0.f,dp6=0.f,dp7=0.f;
#pragma unroll
            for (int q = 0; q < 16; q += 8){
                float4 b0=brow[q+0], b1=brow[q+1], b2=brow[q+2], b3=brow[q+3];
                float4 b4=brow[q+4], b5=brow[q+5], b6=brow[q+6], b7=brow[q+7];
                dp0 += cr4[q+0].x*b0.x + cr4[q+0].y*b0.y + cr4[q+0].z*b0.z + cr4[q+0].w*b0.w;
                dp1 += cr4[q+1].x*b1.x + cr4[q+1].y*b1.y + cr4[q+1].z*b1.z + cr4[q+1].w*b1.w;
                dp2 += cr4[q+2].x*b2.x + cr4[q+2].y*b2.y + cr4[q+2].z*b2.z + cr4[q+2].w*b2.w;
                dp3 += cr4[q+3].x*b3.x + cr4[q+3].y*b3.y + cr4[q+3].z*b3.z + cr4[q+3].w*b3.w;
                dp4 += cr4[q+4].x*b4.x + cr4[q+4].y*b4.y + cr4[q+4].z*b4.z + cr4[q+4].w*b4.w;
                dp5 += cr4[q+5].x*b5.x + cr4[q+5].y*b5.y + cr4[q+5].z*b5.z + cr4[q+5].w*b5.w;
                dp6 += cr4[q+6].x*b6.x + cr4[q+6].y*b6.y + cr4[q+6].z*b6.z + cr4[q+6].w*b6.w;
                dp7 += cr4[q+7].x*b7.x + cr4[q+7].y*b7.y + cr4[q+7].z*b7.z + cr4[q+7].w*b7.w;
            }
            float dot = ((dp0+dp1)+(dp2+dp3)) + ((dp4+dp5)+(dp6+dp7));
            float e   = __expf(fminf(a_l - a_s, 0.f));
            float wsc = (s <= l) ? e * dot : 0.f;          // mask upper triangle
            const float4* xrow = (const float4*)&xds[s*64];
#pragma unroll
            for (int q = 0; q < 16; q++){
                float4 xv = xrow[q];
                acc4[q].x += wsc*xv.x; acc4[q].y += wsc*xv.y;
                acc4[q].z += wsc*xv.z; acc4[q].w += wsc*xv.w;
            }
        }
        u16* yp = brY + (tokbase + l)*Dd + h*Pp;   // overwrite br slice with y
#pragma unroll
        for (int q = 0; q < 16; q++){
            ushort4 o;
            o.x=f2bf(acc4[q].x); o.y=f2bf(acc4[q].y);
            o.z=f2bf(acc4[q].z); o.w=f2bf(acc4[q].w);
            *(ushort4*)(yp + q*4) = o;
        }
    }
}

// ---------------------------------------------------------------------------
// Sequential inter-chunk scan IN PLACE: st[c] := h_prev; carry h.
// ---------------------------------------------------------------------------
template<int DT>
__global__ __launch_bounds__(256) void scan_kernel(
    float* st, const float* __restrict__ Acum, void* d_out, const int* __restrict__ flag)
{
    if (*flag != DT) return;
    const int g = blockIdx.x;
    const int seg = g & 15;
    const int bh = g >> 4;
    const int h = bh & 15, b = bh >> 4;
    const int e = seg*256 + threadIdx.x;
    const float* Ac = Acum + (size_t)(b*Hh + h)*NCc*CLc;
    float hst = 0.f;
    for (int c = 0; c < NCc; c++){
        float dec = __expf(fminf(Ac[c*CLc + 255], 0.f));
        size_t off = ((size_t)((b*NCc + c)*Hh) + h)*4096 + e;
        float s_val = st[off];
        st[off] = hst;
        hst = hst*dec + s_val;
    }
    size_t fi = (size_t)Mm*Dd + (size_t)(b*Hh + h)*4096 + e;
    if (DT) ((u16*)d_out)[fi] = f2bf(hst);
    else    ((float*)d_out)[fi] = hst;
}

// ---------------------------------------------------------------------------
// Y_off[l][p] = exp(a_l) * sum_n cr[l][n] * prev[p][n]; y += Y_off (ws bf16).
// ---------------------------------------------------------------------------
__global__ __launch_bounds__(256) void yoff_kernel(
    const u16* __restrict__ cr, const float* __restrict__ prev,
    const float* __restrict__ Acum, u16* y)
{
    __shared__ float ps[64*65];
    __shared__ u16 crs[256*64];
    const int g = blockIdx.x;
    const int h = g & 15, c = (g >> 4) & 31, b = g >> 9;
    const int t = threadIdx.x;
    const size_t tokbase = (size_t)b*Ll + (size_t)c*CLc;
    const float* pv = prev + ((size_t)((b*NCc + c)*Hh) + h)*4096;
#pragma unroll
    for (int i = 0; i < 16; i++){
        int f = i*256 + t;
        ps[(f >> 6)*65 + (f & 63)] = pv[f];
    }
#pragma unroll
    for (int i = 0; i < 16; i++){
        int f4 = i*256 + t;
        int l  = f4 >> 4;
        int n4 = (f4 & 15)*4;
        *(ushort4*)&crs[l*64 + n4] = *(const ushort4*)&cr[(tokbase + l)*Dd + h*Pp + n4];
    }
    __syncthreads();
    const int w = t >> 6, p = t & 63;
    float acc[64];
#pragma unroll
    for (int j=0;j<64;j++) acc[j]=0.f;
    for (int n = 0; n < 64; n++){
        float pvn = ps[p*65 + n];
#pragma unroll
        for (int j=0;j<64;j++)
            acc[j] += bf2f(crs[(w*64 + j)*64 + n]) * pvn;
    }
    const float* Ac = Acum + ((size_t)(b*Hh + h)*NCc + c)*CLc;
#pragma unroll
    for (int j=0;j<64;j++){
        int l = w*64 + j;
        float el = __expf(fminf(Ac[l], 0.f));
        size_t off = (tokbase + l)*Dd + h*Pp + p;
        y[off] = f2bf(bf2f(y[off]) + el*acc[j]);
    }
}

// ---------------------------------------------------------------------------
__global__ __launch_bounds__(256) void zero_out_kernel(void* o, long long n, const int* flag)
{
    long long i = (long long)blockIdx.x*256 + threadIdx.x;
    if (i < n){
        if (*flag) ((u16*)o)[i] = 0;
        else       ((float*)o)[i] = 0.f;
    }
}

// ---------------------------------------------------------------------------
extern "C" void kernel_launch(void* const* d_in, const int* in_sizes, int n_in,
                              void* d_out, int out_size, void* d_ws, size_t ws_size,
                              hipStream_t stream)
{
    const void* hs   = d_in[0];
    const void* cosb = d_in[1];
    const void* sinb = d_in[2];
    const void* Wc   = d_in[3];
    const void* Wb   = d_in[4];
    const void* Wdt  = d_in[5];
    const void* Wx   = d_in[6];
    const void* Wout = d_in[7];
    // d_in[8] = A, d_in[9] = chunk_size (256, hardcoded)
    const void* Aarr = d_in[8];

    int*  flag  = (int*)d_ws;
    char* wbase = (char*)d_ws + 1024;

    const size_t NEED = 1024
                      + (size_t)3*Mm*Dd*2         // c, b(->y), x(->xdt) bf16
                      + (size_t)Mm*Hh*4           // dt fp32
                      + (size_t)Bb*Hh*Ll*4        // Acum fp32
                      + (size_t)Bb*NCc*Hh*4096*4  // states(->prev) fp32
                      + (size_t)Mm*Dd*2           // hs bf16
                      + (size_t)5*DD2*2;          // Wc^T,Wb^T,Wx^T,Wout^T(hi),Wout^T(lo) bf16

    sniff_kernel<<<1, 64, 0, stream>>>((const unsigned int*)cosb, flag);

    if (ws_size < NEED){
        long long n = (long long)out_size;
        zero_out_kernel<<<(unsigned)((n + 255)/256), 256, 0, stream>>>(d_out, n, flag);
        return;
    }

    u16*   c_buf  = (u16*)wbase;
    u16*   b_buf  = c_buf + (size_t)Mm*Dd;                 // br, then y in place
    u16*   x_buf  = b_buf + (size_t)Mm*Dd;                 // x, then xdt in place
    float* dt_buf = (float*)(x_buf + (size_t)Mm*Dd);
    float* acum   = dt_buf + (size_t)Mm*Hh;
    float* states = acum + (size_t)Bb*Hh*Ll;               // states, then prev
    u16*   hs_bf  = (u16*)(states + (size_t)Bb*NCc*Hh*4096);
    u16*   wt     = hs_bf + (size_t)Mm*Dd;                 // 5 transposed bf16 weights

    // converters (gated on dtype; exactly one set runs)
    cvt_kernel<1><<<(Mm*Dd)/(256*8), 256, 0, stream>>>(hs, hs_bf, flag);
    cvt_kernel<0><<<(Mm*Dd)/(256*8), 256, 0, stream>>>(hs, hs_bf, flag);
    wtrans_kernel<1><<<dim3(16,16,4), 256, 0, stream>>>(Wc, Wb, Wx, Wout, wt, flag);
    wtrans_kernel<0><<<dim3(16,16,4), 256, 0, stream>>>(Wc, Wb, Wx, Wout, wt, flag);

    dt_kernel<1><<<Mm/16, 256, 0, stream>>>(hs, Wdt, dt_buf, flag);
    dt_kernel<0><<<Mm/16, 256, 0, stream>>>(hs, Wdt, dt_buf, flag);

    // projections: bf16 MFMA (operands always ws bf16 -> single ungated launch)
    const int NWG = (Mm/128)*(Dd/128);   // 1024
    gemm_mfma<1,0><<<NWG, 256, 0, stream>>>(hs_bf, wt,         c_buf, Mm, Dd, Dd, flag, -1);
    gemm_mfma<1,0><<<NWG, 256, 0, stream>>>(hs_bf, wt + DD2,   b_buf, Mm, Dd, Dd, flag, -1);
    gemm_mfma<1,0><<<NWG, 256, 0, stream>>>(hs_bf, wt + 2*DD2, x_buf, Mm, Dd, Dd, flag, -1);

    rope_xdt_kernel<1><<<(Mm*Hh*32)/256, 256, 0, stream>>>(c_buf, b_buf, x_buf, dt_buf, cosb, sinb, flag);
    rope_xdt_kernel<0><<<(Mm*Hh*32)/256, 256, 0, stream>>>(c_buf, b_buf, x_buf, dt_buf, cosb, sinb, flag);
    cumsum_kernel<1><<<Bb*Hh*NCc, 256, 0, stream>>>(dt_buf, Aarr, acum, flag);
    cumsum_kernel<0><<<Bb*Hh*NCc, 256, 0, stream>>>(dt_buf, Aarr, acum, flag);
    chunk_kernel<<<Bb*NCc*Hh, 256, 0, stream>>>(c_buf, b_buf, x_buf, acum, states);
    scan_kernel<1><<<Bb*Hh*16, 256, 0, stream>>>(states, acum, d_out, flag);
    scan_kernel<0><<<Bb*Hh*16, 256, 0, stream>>>(states, acum, d_out, flag);
    yoff_kernel<<<Bb*NCc*Hh, 256, 0, stream>>>(c_buf, states, acum, b_buf);

    // output GEMM: bf16 mode -> one bf16 pass; fp32 mode -> Whi pass + Wlo accumulate
    gemm_mfma<1,0><<<NWG, 256, 0, stream>>>(b_buf, wt + 3*DD2, d_out, Mm, Dd, Dd, flag, 1);
    gemm_mfma<0,0><<<NWG, 256, 0, stream>>>(b_buf, wt + 3*DD2, d_out, Mm, Dd, Dd, flag, 0);
    gemm_mfma<0,1><<<NWG, 256, 0, stream>>>(b_buf, wt + 4*DD2, d_out, Mm, Dd, Dd, flag, 0);
}

// Round 4
// 713.288 us; speedup vs baseline: 1.3934x; 1.3934x over previous
//
#include <hip/hip_runtime.h>
#include <hip/hip_bf16.h>

typedef unsigned short u16;

#define Bb 2
#define Ll 8192
#define Dd 1024
#define Hh 16
#define Pp 64
#define CLc 256
#define NCc 32
#define Mm 16384   // B*L
#define DD2 ((size_t)Dd*Dd)

typedef __attribute__((ext_vector_type(8))) short short8b;   // 8 bf16 (4 VGPRs)
typedef __attribute__((ext_vector_type(4))) float f32x4v;    // MFMA C/D

__device__ __forceinline__ float bf2f(u16 u){
    return __uint_as_float(((unsigned int)u) << 16);
}
__device__ __forceinline__ u16 f2bf(float f){
    unsigned int i = __float_as_uint(f);
    unsigned int r = (i + 0x7FFFu + ((i >> 16) & 1u)) >> 16;  // RNE
    return (u16)r;
}

// DT: 1 = bf16, 0 = fp32
template<int DT>
__device__ __forceinline__ float ld1(const void* p, size_t i){
    return DT ? bf2f(((const u16*)p)[i]) : ((const float*)p)[i];
}
template<int DT>
__device__ __forceinline__ void ld8(const void* p, size_t i, float* o){
    if (DT){
        const u16* q = (const u16*)p + i;
        ushort4 a0 = *(const ushort4*)q;
        ushort4 a1 = *(const ushort4*)(q + 4);
        o[0]=bf2f(a0.x); o[1]=bf2f(a0.y); o[2]=bf2f(a0.z); o[3]=bf2f(a0.w);
        o[4]=bf2f(a1.x); o[5]=bf2f(a1.y); o[6]=bf2f(a1.z); o[7]=bf2f(a1.w);
    } else {
        const float* q = (const float*)p + i;
        float4 a0 = *(const float4*)q;
        float4 a1 = *(const float4*)(q + 4);
        o[0]=a0.x; o[1]=a0.y; o[2]=a0.z; o[3]=a0.w;
        o[4]=a1.x; o[5]=a1.y; o[6]=a1.z; o[7]=a1.w;
    }
}

// async global->LDS, 16B per lane; LDS dest must be wave-uniform base (+lane*16 by HW)
typedef __attribute__((address_space(3))) void lds_t;
typedef __attribute__((address_space(1))) const void gm_t;
__device__ __forceinline__ void gload16(const void* g, void* l){
    __builtin_amdgcn_global_load_lds((gm_t*)g, (lds_t*)l, 16, 0, 0);
}

// ---------------------------------------------------------------------------
// Dtype sniff: cos[0] row is 1.0f. fp32 -> 0x3F800000; bf16 -> 0x3F803F80.
// ---------------------------------------------------------------------------
__global__ void sniff_kernel(const unsigned int* __restrict__ cosw, int* __restrict__ flag){
    if (threadIdx.x == 0 && blockIdx.x == 0)
        *flag = (cosw[0] == 0x3F800000u) ? 0 : 1;
}

// ---------------------------------------------------------------------------
// hs -> bf16 workspace copy/convert (gated on dtype).
// ---------------------------------------------------------------------------
template<int DT>
__global__ __launch_bounds__(256) void cvt_kernel(
    const void* __restrict__ in, u16* __restrict__ out, const int* __restrict__ flag)
{
    if (*flag != DT) return;
    size_t i = ((size_t)blockIdx.x*256 + threadIdx.x) * 8;
    float v[8]; ld8<DT>(in, i, v);
    ushort4 o0, o1;
    o0.x=f2bf(v[0]); o0.y=f2bf(v[1]); o0.z=f2bf(v[2]); o0.w=f2bf(v[3]);
    o1.x=f2bf(v[4]); o1.y=f2bf(v[5]); o1.z=f2bf(v[6]); o1.w=f2bf(v[7]);
    *(ushort4*)(out + i)     = o0;
    *(ushort4*)(out + i + 4) = o1;
}

// ---------------------------------------------------------------------------
// Transpose-convert 1024x1024 weights to bf16 W^T (N-major, k-contiguous).
// z selects {Wc,Wb,Wx,Wout}. For Wout (z==3) also emit the bf16x2 low part
// (Wlo = W - bf16(W)) so the fp32-mode output GEMM keeps ~fp32 W precision.
// ---------------------------------------------------------------------------
template<int DT>
__global__ __launch_bounds__(256) void wtrans_kernel(
    const void* __restrict__ W0, const void* __restrict__ W1,
    const void* __restrict__ W2, const void* __restrict__ W3,
    u16* __restrict__ out, const int* __restrict__ flag)
{
    if (*flag != DT) return;
    const int z = blockIdx.z;
    const void* W = (z==0) ? W0 : (z==1) ? W1 : (z==2) ? W2 : W3;
    u16* Whi = out + (size_t)z*DD2;
    u16* Wlo = out + (size_t)4*DD2;
    __shared__ u16 th[64][65];
    __shared__ u16 tlo[64][65];
    const int t = threadIdx.x;
    const int r = t >> 2, cq = (t & 3)*16;
    size_t base = ((size_t)blockIdx.y*64 + r)*1024 + (size_t)blockIdx.x*64 + cq;
    float v[8];
#pragma unroll
    for (int half = 0; half < 2; half++){
        ld8<DT>(W, base + half*8, v);
#pragma unroll
        for (int j = 0; j < 8; j++){
            u16 hi = f2bf(v[j]);
            th[r][cq + half*8 + j]  = hi;
            tlo[r][cq + half*8 + j] = f2bf(v[j] - bf2f(hi));
        }
    }
    __syncthreads();
    size_t ob = ((size_t)blockIdx.x*64 + r)*1024 + (size_t)blockIdx.y*64 + cq;
#pragma unroll
    for (int j = 0; j < 16; j++)
        Whi[ob + j] = th[cq + j][r];
    if (z == 3){
#pragma unroll
        for (int j = 0; j < 16; j++)
            Wlo[ob + j] = tlo[cq + j][r];
    }
}

// ---------------------------------------------------------------------------
// bf16 MFMA GEMM: C[M,N] = A[M,K] @ Bt[N,K]^T  (Bt is the transposed weight).
// ---------------------------------------------------------------------------
template<int DTC, int ACC>
__global__ __launch_bounds__(256) void gemm_mfma(
    const u16* __restrict__ A, const u16* __restrict__ Bt, void* __restrict__ C,
    int M, int N, int K, const int* __restrict__ flag, int want)
{
    if (want >= 0 && *flag != want) return;
    __shared__ __align__(128) u16 As[128*32];   // 8 KB, [row][k]
    __shared__ __align__(128) u16 Bs[128*32];   // 8 KB, [col][k]
    const int t    = threadIdx.x;
    const int wave = t >> 6;
    const int lane = t & 63;

    const int nbn = N >> 7;
    int wg = blockIdx.x, nwg = gridDim.x, swz = wg;
    if ((nwg & 7) == 0){
        int cpx = nwg >> 3;
        swz = (wg & 7)*cpx + (wg >> 3);
    }
    const int bm = swz / nbn, bn = swz % nbn;

    const int ldrow = wave*16 + (lane >> 2);   // 0..63
    const int ldk   = (lane & 3)*8;            // element offset in k
    const u16* Ag0 = A  + (size_t)(bm*128 + ldrow)*K + ldk;
    const u16* Ag1 = Ag0 + (size_t)64*K;
    const u16* Bg0 = Bt + (size_t)(bn*128 + ldrow)*K + ldk;
    const u16* Bg1 = Bg0 + (size_t)64*K;
    u16* AsD0 = &As[(wave*16)*32];
    u16* AsD1 = &As[(64 + wave*16)*32];
    u16* BsD0 = &Bs[(wave*16)*32];
    u16* BsD1 = &Bs[(64 + wave*16)*32];

    const int wr = wave >> 1, wc = wave & 1;
    const int fr = lane & 15;
    const int fk = (lane >> 4)*8;
    const u16* a_rd = &As[(wr*64 + fr)*32 + fk];
    const u16* b_rd = &Bs[(wc*64 + fr)*32 + fk];

    f32x4v acc[4][4] = {};

    for (int k0 = 0; k0 < K; k0 += 32){
        gload16(Ag0 + k0, AsD0);
        gload16(Ag1 + k0, AsD1);
        gload16(Bg0 + k0, BsD0);
        gload16(Bg1 + k0, BsD1);
        __syncthreads();
        short8b af[4], bf[4];
#pragma unroll
        for (int i = 0; i < 4; i++){
            af[i] = *(const short8b*)(a_rd + i*16*32);
            bf[i] = *(const short8b*)(b_rd + i*16*32);
        }
#pragma unroll
        for (int mi = 0; mi < 4; mi++)
#pragma unroll
            for (int ni = 0; ni < 4; ni++)
                acc[mi][ni] = __builtin_amdgcn_mfma_f32_16x16x32_bf16(
                    af[mi], bf[ni], acc[mi][ni], 0, 0, 0);
        __syncthreads();
    }

    const int crow = (lane >> 4)*4;
    const int ccol = lane & 15;
#pragma unroll
    for (int mi = 0; mi < 4; mi++){
#pragma unroll
        for (int ni = 0; ni < 4; ni++){
            size_t col = (size_t)bn*128 + wc*64 + ni*16 + ccol;
#pragma unroll
            for (int r = 0; r < 4; r++){
                size_t row = (size_t)bm*128 + wr*64 + mi*16 + crow + r;
                float v = acc[mi][ni][r];
                if (DTC){
                    ((u16*)C)[row*(size_t)N + col] = f2bf(v);
                } else {
                    float* p = (float*)C + row*(size_t)N + col;
                    *p = ACC ? (*p + v) : v;
                }
            }
        }
    }
}

// ---------------------------------------------------------------------------
// dt = softplus(hs @ Wdt)  (M x 16, K=1024).  16 tokens per block.
// ---------------------------------------------------------------------------
template<int DT>
__global__ __launch_bounds__(256) void dt_kernel(
    const void* __restrict__ hs, const void* __restrict__ Wdt,
    float* __restrict__ dtb, const int* __restrict__ flag)
{
    if (*flag != DT) return;
    __shared__ u16 hss[16*1024];   // 32 KB
    __shared__ u16 wds[1024*16];   // 32 KB
    const int t = threadIdx.x;
    const size_t tok0 = (size_t)blockIdx.x * 16;
    float v[8];
#pragma unroll
    for (int i = 0; i < 8; i++){
        size_t e = (size_t)i*2048 + (size_t)t*8;
        ld8<DT>(hs, tok0*1024 + e, v);
#pragma unroll
        for (int j=0;j<8;j++) hss[e+j] = f2bf(v[j]);
        ld8<DT>(Wdt, e, v);
#pragma unroll
        for (int j=0;j<8;j++) wds[e+j] = f2bf(v[j]);
    }
    __syncthreads();
    const int token = t >> 4, h = t & 15;
    float accv = 0.f;
    for (int k = 0; k < 1024; k++)
        accv += bf2f(hss[token*1024+k]) * bf2f(wds[k*16+h]);
    float sp = (accv > 20.f) ? accv : log1pf(__expf(accv));
    dtb[(tok0 + token)*16 + h] = sp;
}

// ---------------------------------------------------------------------------
// RoPE on c and b (in place, ws bf16) + xdt = x * dt (in place on x buffer).
// ---------------------------------------------------------------------------
template<int DT>
__global__ __launch_bounds__(256) void rope_xdt_kernel(
    u16* cb, u16* bb, u16* xb, const float* __restrict__ dtb,
    const void* __restrict__ cosb, const void* __restrict__ sinb,
    const int* __restrict__ flag)
{
    if (*flag != DT) return;
    const int t = blockIdx.x*256 + threadIdx.x;       // [0, M*H*32)
    const int p = t & 31, h = (t >> 5) & 15;
    const size_t token = (size_t)(t >> 9);
    const size_t base = token*Dd + h*Pp;
    const float cs0 = ld1<DT>(cosb, token*64 + p);
    const float cs1 = ld1<DT>(cosb, token*64 + p + 32);
    const float sn0 = ld1<DT>(sinb, token*64 + p);
    const float sn1 = ld1<DT>(sinb, token*64 + p + 32);
    float c0 = bf2f(cb[base+p]), c1 = bf2f(cb[base+p+32]);
    cb[base+p]    = f2bf(c0*cs0 - c1*sn0);
    cb[base+p+32] = f2bf(c1*cs1 + c0*sn1);
    float b0 = bf2f(bb[base+p]), b1 = bf2f(bb[base+p+32]);
    bb[base+p]    = f2bf(b0*cs0 - b1*sn0);
    bb[base+p+32] = f2bf(b1*cs1 + b0*sn1);
    const float dv = dtb[token*Hh + h];
    xb[base+p]    = f2bf(bf2f(xb[base+p]) * dv);
    xb[base+p+32] = f2bf(bf2f(xb[base+p+32]) * dv);
}

// ---------------------------------------------------------------------------
// Acum[b][h][c][l] = inclusive cumsum over l of dt[token][h]*A[h] per chunk.
// ---------------------------------------------------------------------------
template<int DT>
__global__ __launch_bounds__(256) void cumsum_kernel(
    const float* __restrict__ dtb, const void* __restrict__ Aarr,
    float* __restrict__ Acum, const int* __restrict__ flag)
{
    if (*flag != DT) return;
    const int g = blockIdx.x;
    const int c = g & 31, h = (g >> 5) & 15, b = g >> 9;
    const int l = threadIdx.x;
    __shared__ float s[256];
    const size_t token = (size_t)b*Ll + (size_t)c*CLc + l;
    s[l] = dtb[token*Hh + h] * ld1<DT>(Aarr, h);
    __syncthreads();
    for (int off = 1; off < 256; off <<= 1){
        float add = (l >= off) ? s[l - off] : 0.f;
        __syncthreads();
        s[l] += add;
        __syncthreads();
    }
    Acum[((size_t)(b*Hh + h)*NCc + c)*CLc + l] = s[l];
}

// ---------------------------------------------------------------------------
// Per (b, chunk, h): MFMA version.
//   phase 1: states[p][n] = sum_l xdt[l][p] * (wexp_l * br[l][n])
//            A = xdsT (rows p, k=l), B-op = brTs (rows n, k=l, pre-scaled)
//   phase 2: S = cr @ br^T (A = cr rows l from global, B-op = brs rows s),
//            P = mask(s<=l) * exp(a_l - a_s) * S  -> per-wave LDS tile,
//            Y += P @ xdt (A = P rows l, B-op = xdsT rows p).
// All fragment loads follow the verified gemm_mfma pattern (k-contiguous,
// fr = lane&15, fk = (lane>>4)*8); D layout n=lane&15, m=(lane>>4)*4+reg.
// ---------------------------------------------------------------------------
__global__ __launch_bounds__(256) void chunk_kernel(
    const u16* __restrict__ cr, u16* brY, const u16* __restrict__ xd,
    const float* __restrict__ Acum, float* __restrict__ states)
{
    __shared__ u16 brs[256*72];      // br rows l, k=n (+8 pad)      36.9 KB
    __shared__ u16 brTs[64*264];     // (w*br)^T rows n, k=l (+8)    33.8 KB
    __shared__ u16 xdsT[64*264];     // xdt^T rows p, k=l (+8)       33.8 KB
    __shared__ u16 plds[4][64*72];   // per-wave P tile              36.9 KB
    __shared__ float acs[256];
    __shared__ float wexp[256];
    const int g = blockIdx.x;
    const int h = g & 15, c = (g >> 4) & 31, b = g >> 9;
    const int t = threadIdx.x;
    const int wv = t >> 6, lane = t & 63;
    const size_t tokbase = (size_t)b*Ll + (size_t)c*CLc;
    const float* Ac = Acum + ((size_t)(b*Hh + h)*NCc + c)*CLc;

    const float a_last = Ac[255];
    {
        float av = Ac[t];
        acs[t] = av;
        wexp[t] = __expf(fminf(a_last - av, 0.f));
    }
    __syncthreads();

    // staging: br -> brs (raw) + brTs (scaled transpose); xd -> xdsT
#pragma unroll
    for (int i = 0; i < 8; i++){
        int f8 = i*256 + t;           // 0..2047
        int l  = f8 >> 3;             // 0..255
        int n8 = (f8 & 7)*8;          // 0..56
        size_t goff = (tokbase + l)*Dd + h*Pp + n8;
        ushort4 a0 = *(const ushort4*)&brY[goff];
        ushort4 a1 = *(const ushort4*)&brY[goff + 4];
        *(ushort4*)&brs[l*72 + n8]     = a0;
        *(ushort4*)&brs[l*72 + n8 + 4] = a1;
        float wl = wexp[l];
        u16 bv[8] = {(u16)a0.x,(u16)a0.y,(u16)a0.z,(u16)a0.w,
                     (u16)a1.x,(u16)a1.y,(u16)a1.z,(u16)a1.w};
#pragma unroll
        for (int j = 0; j < 8; j++)
            brTs[(n8 + j)*264 + l] = f2bf(wl * bf2f(bv[j]));
        ushort4 x0 = *(const ushort4*)&xd[goff];
        ushort4 x1 = *(const ushort4*)&xd[goff + 4];
        u16 xv[8] = {(u16)x0.x,(u16)x0.y,(u16)x0.z,(u16)x0.w,
                     (u16)x1.x,(u16)x1.y,(u16)x1.z,(u16)x1.w};
#pragma unroll
        for (int j = 0; j < 8; j++)
            xdsT[(n8 + j)*264 + l] = xv[j];
    }
    __syncthreads();

    const int fr = lane & 15;
    const int kb = (lane >> 4)*8;

    // ---------------- phase 1: states (wave wv owns p-frag pi = wv) --------
    {
        int ks0 = 0;
        for (int ks = 0; ks < 8; ks++){
            if (a_last - acs[ks*32 + 31] >= -30.f){ ks0 = ks; break; }
        }
        f32x4v sacc[4] = {};
        const int pr = wv*16 + fr;
        for (int ks = ks0; ks < 8; ks++){
            short8b afr = *(const short8b*)&xdsT[pr*264 + ks*32 + kb];
#pragma unroll
            for (int ni = 0; ni < 4; ni++){
                short8b bfr = *(const short8b*)&brTs[(ni*16 + fr)*264 + ks*32 + kb];
                sacc[ni] = __builtin_amdgcn_mfma_f32_16x16x32_bf16(afr, bfr, sacc[ni], 0, 0, 0);
            }
        }
        float* st = states + ((size_t)((b*NCc + c)*Hh) + h)*4096;
        const int prow = wv*16 + (lane >> 4)*4;
#pragma unroll
        for (int ni = 0; ni < 4; ni++)
#pragma unroll
            for (int r = 0; r < 4; r++)
                st[(prow + r)*64 + ni*16 + fr] = sacc[ni][r];
    }

    // ---------------- phase 2: Y_diag (wave wv owns l-rows [wv*64, +64)) ---
    {
        // cr A-frags (global/L2, k-contiguous)
        short8b crf[4][2];
#pragma unroll
        for (int mi = 0; mi < 4; mi++)
#pragma unroll
            for (int ks = 0; ks < 2; ks++)
                crf[mi][ks] = *(const short8b*)&cr[(tokbase + wv*64 + mi*16 + fr)*Dd + h*Pp + ks*32 + kb];

        float al[4][4];
#pragma unroll
        for (int mi = 0; mi < 4; mi++)
#pragma unroll
            for (int r = 0; r < 4; r++)
                al[mi][r] = acs[wv*64 + mi*16 + (lane >> 4)*4 + r];

        f32x4v yacc[4][4] = {};   // [mi][pi]
        u16* pw = &plds[wv][0];
        const float a_hi = acs[wv*64];

        for (int cb = wv; cb >= 0; --cb){
            if (a_hi - acs[cb*64 + 63] < -30.f) break;   // whole tile dead
            // S tile -> mask/exp -> P (bf16, per-wave LDS)
#pragma unroll
            for (int mi = 0; mi < 4; mi++){
#pragma unroll
                for (int ni = 0; ni < 4; ni++){
                    f32x4v s4 = {};
#pragma unroll
                    for (int ks = 0; ks < 2; ks++){
                        short8b bfr = *(const short8b*)&brs[(cb*64 + ni*16 + fr)*72 + ks*32 + kb];
                        s4 = __builtin_amdgcn_mfma_f32_16x16x32_bf16(crf[mi][ks], bfr, s4, 0, 0, 0);
                    }
                    const int s_idx = cb*64 + ni*16 + fr;
                    const float a_s = acs[s_idx];
                    const int lrow0 = wv*64 + mi*16 + (lane >> 4)*4;
#pragma unroll
                    for (int r = 0; r < 4; r++){
                        float w  = __expf(fminf(al[mi][r] - a_s, 0.f));
                        float pv = (s_idx <= lrow0 + r) ? w * s4[r] : 0.f;
                        pw[(mi*16 + (lane >> 4)*4 + r)*72 + ni*16 + fr] = f2bf(pv);
                    }
                }
            }
            asm volatile("s_waitcnt lgkmcnt(0)" ::: "memory");
            // PV: yacc += P @ xdt-block
#pragma unroll
            for (int ks = 0; ks < 2; ks++){
                short8b paf[4];
#pragma unroll
                for (int mi = 0; mi < 4; mi++)
                    paf[mi] = *(const short8b*)&pw[(mi*16 + fr)*72 + ks*32 + kb];
#pragma unroll
                for (int pi = 0; pi < 4; pi++){
                    short8b xbf = *(const short8b*)&xdsT[(pi*16 + fr)*264 + cb*64 + ks*32 + kb];
#pragma unroll
                    for (int mi = 0; mi < 4; mi++)
                        yacc[mi][pi] = __builtin_amdgcn_mfma_f32_16x16x32_bf16(paf[mi], xbf, yacc[mi][pi], 0, 0, 0);
                }
            }
        }
        // write Y over br slice
#pragma unroll
        for (int mi = 0; mi < 4; mi++){
            const int lrow = wv*64 + mi*16 + (lane >> 4)*4;
#pragma unroll
            for (int r = 0; r < 4; r++){
                u16* yp = brY + (tokbase + lrow + r)*Dd + h*Pp + fr;
#pragma unroll
                for (int pi = 0; pi < 4; pi++)
                    yp[pi*16] = f2bf(yacc[mi][pi][r]);
            }
        }
    }
}

// ---------------------------------------------------------------------------
// Sequential inter-chunk scan IN PLACE: st[c] := h_prev; carry h.
// ---------------------------------------------------------------------------
template<int DT>
__global__ __launch_bounds__(256) void scan_kernel(
    float* st, const float* __restrict__ Acum, void* d_out, const int* __restrict__ flag)
{
    if (*flag != DT) return;
    const int g = blockIdx.x;
    const int seg = g & 15;
    const int bh = g >> 4;
    const int h = bh & 15, b = bh >> 4;
    const int e = seg*256 + threadIdx.x;
    const float* Ac = Acum + (size_t)(b*Hh + h)*NCc*CLc;
    float hst = 0.f;
    for (int c = 0; c < NCc; c++){
        float dec = __expf(fminf(Ac[c*CLc + 255], 0.f));
        size_t off = ((size_t)((b*NCc + c)*Hh) + h)*4096 + e;
        float s_val = st[off];
        st[off] = hst;
        hst = hst*dec + s_val;
    }
    size_t fi = (size_t)Mm*Dd + (size_t)(b*Hh + h)*4096 + e;
    if (DT) ((u16*)d_out)[fi] = f2bf(hst);
    else    ((float*)d_out)[fi] = hst;
}

// ---------------------------------------------------------------------------
// Y_off[l][p] = exp(a_l) * sum_n cr[l][n] * prev[p][n]; y += Y_off (ws bf16).
// ---------------------------------------------------------------------------
__global__ __launch_bounds__(256) void yoff_kernel(
    const u16* __restrict__ cr, const float* __restrict__ prev,
    const float* __restrict__ Acum, u16* y)
{
    __shared__ float ps[64*65];
    __shared__ u16 crs[256*64];
    const int g = blockIdx.x;
    const int h = g & 15, c = (g >> 4) & 31, b = g >> 9;
    const int t = threadIdx.x;
    const size_t tokbase = (size_t)b*Ll + (size_t)c*CLc;
    const float* pv = prev + ((size_t)((b*NCc + c)*Hh) + h)*4096;
#pragma unroll
    for (int i = 0; i < 16; i++){
        int f = i*256 + t;
        ps[(f >> 6)*65 + (f & 63)] = pv[f];
    }
#pragma unroll
    for (int i = 0; i < 16; i++){
        int f4 = i*256 + t;
        int l  = f4 >> 4;
        int n4 = (f4 & 15)*4;
        *(ushort4*)&crs[l*64 + n4] = *(const ushort4*)&cr[(tokbase + l)*Dd + h*Pp + n4];
    }
    __syncthreads();
    const int w = t >> 6, p = t & 63;
    float acc[64];
#pragma unroll
    for (int j=0;j<64;j++) acc[j]=0.f;
    for (int n = 0; n < 64; n++){
        float pvn = ps[p*65 + n];
#pragma unroll
        for (int j=0;j<64;j++)
            acc[j] += bf2f(crs[(w*64 + j)*64 + n]) * pvn;
    }
    const float* Ac = Acum + ((size_t)(b*Hh + h)*NCc + c)*CLc;
#pragma unroll
    for (int j=0;j<64;j++){
        int l = w*64 + j;
        float el = __expf(fminf(Ac[l], 0.f));
        size_t off = (tokbase + l)*Dd + h*Pp + p;
        y[off] = f2bf(bf2f(y[off]) + el*acc[j]);
    }
}

// ---------------------------------------------------------------------------
__global__ __launch_bounds__(256) void zero_out_kernel(void* o, long long n, const int* flag)
{
    long long i = (long long)blockIdx.x*256 + threadIdx.x;
    if (i < n){
        if (*flag) ((u16*)o)[i] = 0;
        else       ((float*)o)[i] = 0.f;
    }
}

// ---------------------------------------------------------------------------
extern "C" void kernel_launch(void* const* d_in, const int* in_sizes, int n_in,
                              void* d_out, int out_size, void* d_ws, size_t ws_size,
                              hipStream_t stream)
{
    const void* hs   = d_in[0];
    const void* cosb = d_in[1];
    const void* sinb = d_in[2];
    const void* Wc   = d_in[3];
    const void* Wb   = d_in[4];
    const void* Wdt  = d_in[5];
    const void* Wx   = d_in[6];
    const void* Wout = d_in[7];
    const void* Aarr = d_in[8];
    // d_in[9] = chunk_size (256, hardcoded)

    int*  flag  = (int*)d_ws;
    char* wbase = (char*)d_ws + 1024;

    const size_t NEED = 1024
                      + (size_t)3*Mm*Dd*2         // c, b(->y), x(->xdt) bf16
                      + (size_t)Mm*Hh*4           // dt fp32
                      + (size_t)Bb*Hh*Ll*4        // Acum fp32
                      + (size_t)Bb*NCc*Hh*4096*4  // states(->prev) fp32
                      + (size_t)Mm*Dd*2           // hs bf16
                      + (size_t)5*DD2*2;          // W^T bf16 x5

    sniff_kernel<<<1, 64, 0, stream>>>((const unsigned int*)cosb, flag);

    if (ws_size < NEED){
        long long n = (long long)out_size;
        zero_out_kernel<<<(unsigned)((n + 255)/256), 256, 0, stream>>>(d_out, n, flag);
        return;
    }

    u16*   c_buf  = (u16*)wbase;
    u16*   b_buf  = c_buf + (size_t)Mm*Dd;                 // br, then y in place
    u16*   x_buf  = b_buf + (size_t)Mm*Dd;                 // x, then xdt in place
    float* dt_buf = (float*)(x_buf + (size_t)Mm*Dd);
    float* acum   = dt_buf + (size_t)Mm*Hh;
    float* states = acum + (size_t)Bb*Hh*Ll;               // states, then prev
    u16*   hs_bf  = (u16*)(states + (size_t)Bb*NCc*Hh*4096);
    u16*   wt     = hs_bf + (size_t)Mm*Dd;                 // 5 transposed bf16 weights

    cvt_kernel<1><<<(Mm*Dd)/(256*8), 256, 0, stream>>>(hs, hs_bf, flag);
    cvt_kernel<0><<<(Mm*Dd)/(256*8), 256, 0, stream>>>(hs, hs_bf, flag);
    wtrans_kernel<1><<<dim3(16,16,4), 256, 0, stream>>>(Wc, Wb, Wx, Wout, wt, flag);
    wtrans_kernel<0><<<dim3(16,16,4), 256, 0, stream>>>(Wc, Wb, Wx, Wout, wt, flag);

    dt_kernel<1><<<Mm/16, 256, 0, stream>>>(hs, Wdt, dt_buf, flag);
    dt_kernel<0><<<Mm/16, 256, 0, stream>>>(hs, Wdt, dt_buf, flag);

    const int NWG = (Mm/128)*(Dd/128);   // 1024
    gemm_mfma<1,0><<<NWG, 256, 0, stream>>>(hs_bf, wt,         c_buf, Mm, Dd, Dd, flag, -1);
    gemm_mfma<1,0><<<NWG, 256, 0, stream>>>(hs_bf, wt + DD2,   b_buf, Mm, Dd, Dd, flag, -1);
    gemm_mfma<1,0><<<NWG, 256, 0, stream>>>(hs_bf, wt + 2*DD2, x_buf, Mm, Dd, Dd, flag, -1);

    rope_xdt_kernel<1><<<(Mm*Hh*32)/256, 256, 0, stream>>>(c_buf, b_buf, x_buf, dt_buf, cosb, sinb, flag);
    rope_xdt_kernel<0><<<(Mm*Hh*32)/256, 256, 0, stream>>>(c_buf, b_buf, x_buf, dt_buf, cosb, sinb, flag);
    cumsum_kernel<1><<<Bb*Hh*NCc, 256, 0, stream>>>(dt_buf, Aarr, acum, flag);
    cumsum_kernel<0><<<Bb*Hh*NCc, 256, 0, stream>>>(dt_buf, Aarr, acum, flag);
    chunk_kernel<<<Bb*NCc*Hh, 256, 0, stream>>>(c_buf, b_buf, x_buf, acum, states);
    scan_kernel<1><<<Bb*Hh*16, 256, 0, stream>>>(states, acum, d_out, flag);
    scan_kernel<0><<<Bb*Hh*16, 256, 0, stream>>>(states, acum, d_out, flag);
    yoff_kernel<<<Bb*NCc*Hh, 256, 0, stream>>>(c_buf, states, acum, b_buf);

    gemm_mfma<1,0><<<NWG, 256, 0, stream>>>(b_buf, wt + 3*DD2, d_out, Mm, Dd, Dd, flag, 1);
    gemm_mfma<0,0><<<NWG, 256, 0, stream>>>(b_buf, wt + 3*DD2, d_out, Mm, Dd, Dd, flag, 0);
    gemm_mfma<0,1><<<NWG, 256, 0, stream>>>(b_buf, wt + 4*DD2, d_out, Mm, Dd, Dd, flag, 0);
}

// Round 5
// 656.710 us; speedup vs baseline: 1.5134x; 1.0862x over previous
//
#include <hip/hip_runtime.h>
#include <hip/hip_bf16.h>

typedef unsigned short u16;

#define Bb 2
#define Ll 8192
#define Dd 1024
#define Hh 16
#define Pp 64
#define CLc 256
#define NCc 32
#define Mm 16384   // B*L
#define DD2 ((size_t)Dd*Dd)

typedef __attribute__((ext_vector_type(8))) short short8b;   // 8 bf16 (4 VGPRs)
typedef __attribute__((ext_vector_type(4))) float f32x4v;    // MFMA C/D

__device__ __forceinline__ float bf2f(u16 u){
    return __uint_as_float(((unsigned int)u) << 16);
}
__device__ __forceinline__ u16 f2bf(float f){
    unsigned int i = __float_as_uint(f);
    unsigned int r = (i + 0x7FFFu + ((i >> 16) & 1u)) >> 16;  // RNE
    return (u16)r;
}

// DT: 1 = bf16, 0 = fp32
template<int DT>
__device__ __forceinline__ float ld1(const void* p, size_t i){
    return DT ? bf2f(((const u16*)p)[i]) : ((const float*)p)[i];
}
template<int DT>
__device__ __forceinline__ void ld8(const void* p, size_t i, float* o){
    if (DT){
        const u16* q = (const u16*)p + i;
        ushort4 a0 = *(const ushort4*)q;
        ushort4 a1 = *(const ushort4*)(q + 4);
        o[0]=bf2f(a0.x); o[1]=bf2f(a0.y); o[2]=bf2f(a0.z); o[3]=bf2f(a0.w);
        o[4]=bf2f(a1.x); o[5]=bf2f(a1.y); o[6]=bf2f(a1.z); o[7]=bf2f(a1.w);
    } else {
        const float* q = (const float*)p + i;
        float4 a0 = *(const float4*)q;
        float4 a1 = *(const float4*)(q + 4);
        o[0]=a0.x; o[1]=a0.y; o[2]=a0.z; o[3]=a0.w;
        o[4]=a1.x; o[5]=a1.y; o[6]=a1.z; o[7]=a1.w;
    }
}

// async global->LDS, 16B per lane; LDS dest must be wave-uniform base (+lane*16 by HW)
typedef __attribute__((address_space(3))) void lds_t;
typedef __attribute__((address_space(1))) const void gm_t;
__device__ __forceinline__ void gload16(const void* g, void* l){
    __builtin_amdgcn_global_load_lds((gm_t*)g, (lds_t*)l, 16, 0, 0);
}

// ---------------------------------------------------------------------------
// Dtype sniff: cos[0] row is 1.0f. fp32 -> 0x3F800000; bf16 -> 0x3F803F80.
// ---------------------------------------------------------------------------
__global__ void sniff_kernel(const unsigned int* __restrict__ cosw, int* __restrict__ flag){
    if (threadIdx.x == 0 && blockIdx.x == 0)
        *flag = (cosw[0] == 0x3F800000u) ? 0 : 1;
}

// ---------------------------------------------------------------------------
// hs -> bf16 workspace copy/convert (gated on dtype).
// ---------------------------------------------------------------------------
template<int DT>
__global__ __launch_bounds__(256) void cvt_kernel(
    const void* __restrict__ in, u16* __restrict__ out, const int* __restrict__ flag)
{
    if (*flag != DT) return;
    size_t i = ((size_t)blockIdx.x*256 + threadIdx.x) * 8;
    float v[8]; ld8<DT>(in, i, v);
    ushort4 o0, o1;
    o0.x=f2bf(v[0]); o0.y=f2bf(v[1]); o0.z=f2bf(v[2]); o0.w=f2bf(v[3]);
    o1.x=f2bf(v[4]); o1.y=f2bf(v[5]); o1.z=f2bf(v[6]); o1.w=f2bf(v[7]);
    *(ushort4*)(out + i)     = o0;
    *(ushort4*)(out + i + 4) = o1;
}

// ---------------------------------------------------------------------------
// Transpose-convert 1024x1024 weights to bf16 W^T (N-major, k-contiguous).
// z selects {Wc,Wb,Wx,Wout}. For Wout (z==3) also emit the bf16x2 low part
// (Wlo = W - bf16(W)) so the fp32-mode output GEMM keeps ~fp32 W precision.
// ---------------------------------------------------------------------------
template<int DT>
__global__ __launch_bounds__(256) void wtrans_kernel(
    const void* __restrict__ W0, const void* __restrict__ W1,
    const void* __restrict__ W2, const void* __restrict__ W3,
    u16* __restrict__ out, const int* __restrict__ flag)
{
    if (*flag != DT) return;
    const int z = blockIdx.z;
    const void* W = (z==0) ? W0 : (z==1) ? W1 : (z==2) ? W2 : W3;
    u16* Whi = out + (size_t)z*DD2;
    u16* Wlo = out + (size_t)4*DD2;
    __shared__ u16 th[64][65];
    __shared__ u16 tlo[64][65];
    const int t = threadIdx.x;
    const int r = t >> 2, cq = (t & 3)*16;
    size_t base = ((size_t)blockIdx.y*64 + r)*1024 + (size_t)blockIdx.x*64 + cq;
    float v[8];
#pragma unroll
    for (int half = 0; half < 2; half++){
        ld8<DT>(W, base + half*8, v);
#pragma unroll
        for (int j = 0; j < 8; j++){
            u16 hi = f2bf(v[j]);
            th[r][cq + half*8 + j]  = hi;
            tlo[r][cq + half*8 + j] = f2bf(v[j] - bf2f(hi));
        }
    }
    __syncthreads();
    size_t ob = ((size_t)blockIdx.x*64 + r)*1024 + (size_t)blockIdx.y*64 + cq;
#pragma unroll
    for (int j = 0; j < 16; j++)
        Whi[ob + j] = th[cq + j][r];
    if (z == 3){
#pragma unroll
        for (int j = 0; j < 16; j++)
            Wlo[ob + j] = tlo[cq + j][r];
    }
}

// ---------------------------------------------------------------------------
// bf16 MFMA GEMM: C[M,N] = A[M,K] @ Bt[N,K]^T  (Bt is the transposed weight).
// 2-phase double-buffered staging (T3-min): issue K-step t+1's
// global_load_lds BEFORE computing step t from the other buffer; one
// barrier per step.  The prefetch latency hides under ds_read+MFMA and
// co-resident blocks.
// DTC: 1 -> bf16 C, 0 -> fp32 C.  ACC: 1 -> C += (fp32 only).
// FUSE: 1 -> N spans 3 contiguous output buffers of [M][1024] each
//        (bn>>3 selects buffer, bn&7 the 128-col tile inside it).
// want: -1 ungated, else require *flag == want.
// ---------------------------------------------------------------------------
template<int DTC, int ACC, int FUSE>
__global__ __launch_bounds__(256) void gemm_mfma(
    const u16* __restrict__ A, const u16* __restrict__ Bt, void* __restrict__ C,
    int M, int N, int K, const int* __restrict__ flag, int want)
{
    if (want >= 0 && *flag != want) return;
    __shared__ __align__(128) u16 As[2][128*32];   // 16 KB
    __shared__ __align__(128) u16 Bs[2][128*32];   // 16 KB
    const int t    = threadIdx.x;
    const int wave = t >> 6;
    const int lane = t & 63;

    // XCD-aware bijective block swizzle (grid % 8 == 0 for all our shapes)
    const int nbn = N >> 7;
    int wg = blockIdx.x, nwg = gridDim.x, swz = wg;
    if ((nwg & 7) == 0){
        int cpx = nwg >> 3;
        swz = (wg & 7)*cpx + (wg >> 3);
    }
    const int bm = swz / nbn, bn = swz % nbn;

    // staging: each wave's gload covers 16 rows (64 lanes x 16B = 1024B)
    const int ldrow = wave*16 + (lane >> 2);   // 0..63
    const int ldk   = (lane & 3)*8;            // element offset in k
    const u16* Ag0 = A  + (size_t)(bm*128 + ldrow)*K + ldk;
    const u16* Ag1 = Ag0 + (size_t)64*K;
    const u16* Bg0 = Bt + (size_t)(bn*128 + ldrow)*K + ldk;
    const u16* Bg1 = Bg0 + (size_t)64*K;
    const int o0 = (wave*16)*32;               // wave-uniform LDS offsets
    const int o1 = (64 + wave*16)*32;

    // compute: wave (wr,wc) owns a 64x64 sub-tile
    const int wr = wave >> 1, wc = wave & 1;
    const int fr = lane & 15;                  // fragment row/col
    const int fk = (lane >> 4)*8;              // fragment k base

    f32x4v acc[4][4] = {};

    // prologue: stage step 0 into buffer 0
    gload16(Ag0, &As[0][o0]);
    gload16(Ag1, &As[0][o1]);
    gload16(Bg0, &Bs[0][o0]);
    gload16(Bg1, &Bs[0][o1]);
    __syncthreads();

    int cur = 0;
    for (int k0 = 0; k0 < K; k0 += 32){
        const int nxt = cur ^ 1;
        if (k0 + 32 < K){                      // prefetch next K-step
            gload16(Ag0 + k0 + 32, &As[nxt][o0]);
            gload16(Ag1 + k0 + 32, &As[nxt][o1]);
            gload16(Bg0 + k0 + 32, &Bs[nxt][o0]);
            gload16(Bg1 + k0 + 32, &Bs[nxt][o1]);
        }
        const u16* a_rd = &As[cur][(wr*64 + fr)*32 + fk];
        const u16* b_rd = &Bs[cur][(wc*64 + fr)*32 + fk];
        short8b af[4], bfv[4];
#pragma unroll
        for (int i = 0; i < 4; i++){
            af[i]  = *(const short8b*)(a_rd + i*16*32);
            bfv[i] = *(const short8b*)(b_rd + i*16*32);
        }
#pragma unroll
        for (int mi = 0; mi < 4; mi++)
#pragma unroll
            for (int ni = 0; ni < 4; ni++)
                acc[mi][ni] = __builtin_amdgcn_mfma_f32_16x16x32_bf16(
                    af[mi], bfv[ni], acc[mi][ni], 0, 0, 0);
        __syncthreads();                       // drains prefetch + lds reads
        cur = nxt;
    }

    // epilogue: C/D layout col=lane&15, row=(lane>>4)*4+reg  [verified]
    const int crow = (lane >> 4)*4;
    const int ccol = lane & 15;
    // FUSE: pick one of 3 contiguous [M][1024] buffers by bn>>3
    u16* Cf = FUSE ? ((u16*)C + (size_t)(bn >> 3)*((size_t)Mm*Dd)) : (u16*)C;
    const int bnl = FUSE ? (bn & 7) : bn;
    const size_t Nout = FUSE ? (size_t)Dd : (size_t)N;
#pragma unroll
    for (int mi = 0; mi < 4; mi++){
#pragma unroll
        for (int ni = 0; ni < 4; ni++){
            size_t col = (size_t)bnl*128 + wc*64 + ni*16 + ccol;
#pragma unroll
            for (int r = 0; r < 4; r++){
                size_t row = (size_t)bm*128 + wr*64 + mi*16 + crow + r;
                float v = acc[mi][ni][r];
                if (DTC){
                    Cf[row*Nout + col] = f2bf(v);
                } else {
                    float* p = (float*)C + row*Nout + col;
                    *p = ACC ? (*p + v) : v;
                }
            }
        }
    }
}

// ---------------------------------------------------------------------------
// dt = softplus(hs @ Wdt)  (M x 16, K=1024).  16 tokens per block.
// ---------------------------------------------------------------------------
template<int DT>
__global__ __launch_bounds__(256) void dt_kernel(
    const void* __restrict__ hs, const void* __restrict__ Wdt,
    float* __restrict__ dtb, const int* __restrict__ flag)
{
    if (*flag != DT) return;
    __shared__ u16 hss[16*1024];   // 32 KB
    __shared__ u16 wds[1024*16];   // 32 KB
    const int t = threadIdx.x;
    const size_t tok0 = (size_t)blockIdx.x * 16;
    float v[8];
#pragma unroll
    for (int i = 0; i < 8; i++){
        size_t e = (size_t)i*2048 + (size_t)t*8;
        ld8<DT>(hs, tok0*1024 + e, v);
#pragma unroll
        for (int j=0;j<8;j++) hss[e+j] = f2bf(v[j]);
        ld8<DT>(Wdt, e, v);
#pragma unroll
        for (int j=0;j<8;j++) wds[e+j] = f2bf(v[j]);
    }
    __syncthreads();
    const int token = t >> 4, h = t & 15;
    float accv = 0.f;
    for (int k = 0; k < 1024; k++)
        accv += bf2f(hss[token*1024+k]) * bf2f(wds[k*16+h]);
    float sp = (accv > 20.f) ? accv : log1pf(__expf(accv));
    dtb[(tok0 + token)*16 + h] = sp;
}

// ---------------------------------------------------------------------------
// RoPE on c and b (in place, ws bf16) + xdt = x * dt (in place on x buffer).
// ---------------------------------------------------------------------------
template<int DT>
__global__ __launch_bounds__(256) void rope_xdt_kernel(
    u16* cb, u16* bb, u16* xb, const float* __restrict__ dtb,
    const void* __restrict__ cosb, const void* __restrict__ sinb,
    const int* __restrict__ flag)
{
    if (*flag != DT) return;
    const int t = blockIdx.x*256 + threadIdx.x;       // [0, M*H*32)
    const int p = t & 31, h = (t >> 5) & 15;
    const size_t token = (size_t)(t >> 9);
    const size_t base = token*Dd + h*Pp;
    const float cs0 = ld1<DT>(cosb, token*64 + p);
    const float cs1 = ld1<DT>(cosb, token*64 + p + 32);
    const float sn0 = ld1<DT>(sinb, token*64 + p);
    const float sn1 = ld1<DT>(sinb, token*64 + p + 32);
    float c0 = bf2f(cb[base+p]), c1 = bf2f(cb[base+p+32]);
    cb[base+p]    = f2bf(c0*cs0 - c1*sn0);
    cb[base+p+32] = f2bf(c1*cs1 + c0*sn1);
    float b0 = bf2f(bb[base+p]), b1 = bf2f(bb[base+p+32]);
    bb[base+p]    = f2bf(b0*cs0 - b1*sn0);
    bb[base+p+32] = f2bf(b1*cs1 + b0*sn1);
    const float dv = dtb[token*Hh + h];
    xb[base+p]    = f2bf(bf2f(xb[base+p]) * dv);
    xb[base+p+32] = f2bf(bf2f(xb[base+p+32]) * dv);
}

// ---------------------------------------------------------------------------
// Acum[b][h][c][l] = inclusive cumsum over l of dt[token][h]*A[h] per chunk.
// ---------------------------------------------------------------------------
template<int DT>
__global__ __launch_bounds__(256) void cumsum_kernel(
    const float* __restrict__ dtb, const void* __restrict__ Aarr,
    float* __restrict__ Acum, const int* __restrict__ flag)
{
    if (*flag != DT) return;
    const int g = blockIdx.x;
    const int c = g & 31, h = (g >> 5) & 15, b = g >> 9;
    const int l = threadIdx.x;
    __shared__ float s[256];
    const size_t token = (size_t)b*Ll + (size_t)c*CLc + l;
    s[l] = dtb[token*Hh + h] * ld1<DT>(Aarr, h);
    __syncthreads();
    for (int off = 1; off < 256; off <<= 1){
        float add = (l >= off) ? s[l - off] : 0.f;
        __syncthreads();
        s[l] += add;
        __syncthreads();
    }
    Acum[((size_t)(b*Hh + h)*NCc + c)*CLc + l] = s[l];
}

// ---------------------------------------------------------------------------
// Per (b, chunk, h): MFMA version (verified r4).
// ---------------------------------------------------------------------------
__global__ __launch_bounds__(256) void chunk_kernel(
    const u16* __restrict__ cr, u16* brY, const u16* __restrict__ xd,
    const float* __restrict__ Acum, float* __restrict__ states)
{
    __shared__ u16 brs[256*72];      // br rows l, k=n (+8 pad)      36.9 KB
    __shared__ u16 brTs[64*264];     // (w*br)^T rows n, k=l (+8)    33.8 KB
    __shared__ u16 xdsT[64*264];     // xdt^T rows p, k=l (+8)       33.8 KB
    __shared__ u16 plds[4][64*72];   // per-wave P tile              36.9 KB
    __shared__ float acs[256];
    __shared__ float wexp[256];
    const int g = blockIdx.x;
    const int h = g & 15, c = (g >> 4) & 31, b = g >> 9;
    const int t = threadIdx.x;
    const int wv = t >> 6, lane = t & 63;
    const size_t tokbase = (size_t)b*Ll + (size_t)c*CLc;
    const float* Ac = Acum + ((size_t)(b*Hh + h)*NCc + c)*CLc;

    const float a_last = Ac[255];
    {
        float av = Ac[t];
        acs[t] = av;
        wexp[t] = __expf(fminf(a_last - av, 0.f));
    }
    __syncthreads();

    // staging: br -> brs (raw) + brTs (scaled transpose); xd -> xdsT
#pragma unroll
    for (int i = 0; i < 8; i++){
        int f8 = i*256 + t;           // 0..2047
        int l  = f8 >> 3;             // 0..255
        int n8 = (f8 & 7)*8;          // 0..56
        size_t goff = (tokbase + l)*Dd + h*Pp + n8;
        ushort4 a0 = *(const ushort4*)&brY[goff];
        ushort4 a1 = *(const ushort4*)&brY[goff + 4];
        *(ushort4*)&brs[l*72 + n8]     = a0;
        *(ushort4*)&brs[l*72 + n8 + 4] = a1;
        float wl = wexp[l];
        u16 bv[8] = {(u16)a0.x,(u16)a0.y,(u16)a0.z,(u16)a0.w,
                     (u16)a1.x,(u16)a1.y,(u16)a1.z,(u16)a1.w};
#pragma unroll
        for (int j = 0; j < 8; j++)
            brTs[(n8 + j)*264 + l] = f2bf(wl * bf2f(bv[j]));
        ushort4 x0 = *(const ushort4*)&xd[goff];
        ushort4 x1 = *(const ushort4*)&xd[goff + 4];
        u16 xv[8] = {(u16)x0.x,(u16)x0.y,(u16)x0.z,(u16)x0.w,
                     (u16)x1.x,(u16)x1.y,(u16)x1.z,(u16)x1.w};
#pragma unroll
        for (int j = 0; j < 8; j++)
            xdsT[(n8 + j)*264 + l] = xv[j];
    }
    __syncthreads();

    const int fr = lane & 15;
    const int kb = (lane >> 4)*8;

    // ---------------- phase 1: states (wave wv owns p-frag pi = wv) --------
    {
        int ks0 = 0;
        for (int ks = 0; ks < 8; ks++){
            if (a_last - acs[ks*32 + 31] >= -30.f){ ks0 = ks; break; }
        }
        f32x4v sacc[4] = {};
        const int pr = wv*16 + fr;
        for (int ks = ks0; ks < 8; ks++){
            short8b afr = *(const short8b*)&xdsT[pr*264 + ks*32 + kb];
#pragma unroll
            for (int ni = 0; ni < 4; ni++){
                short8b bfr = *(const short8b*)&brTs[(ni*16 + fr)*264 + ks*32 + kb];
                sacc[ni] = __builtin_amdgcn_mfma_f32_16x16x32_bf16(afr, bfr, sacc[ni], 0, 0, 0);
            }
        }
        float* st = states + ((size_t)((b*NCc + c)*Hh) + h)*4096;
        const int prow = wv*16 + (lane >> 4)*4;
#pragma unroll
        for (int ni = 0; ni < 4; ni++)
#pragma unroll
            for (int r = 0; r < 4; r++)
                st[(prow + r)*64 + ni*16 + fr] = sacc[ni][r];
    }

    // ---------------- phase 2: Y_diag (wave wv owns l-rows [wv*64, +64)) ---
    {
        short8b crf[4][2];
#pragma unroll
        for (int mi = 0; mi < 4; mi++)
#pragma unroll
            for (int ks = 0; ks < 2; ks++)
                crf[mi][ks] = *(const short8b*)&cr[(tokbase + wv*64 + mi*16 + fr)*Dd + h*Pp + ks*32 + kb];

        float al[4][4];
#pragma unroll
        for (int mi = 0; mi < 4; mi++)
#pragma unroll
            for (int r = 0; r < 4; r++)
                al[mi][r] = acs[wv*64 + mi*16 + (lane >> 4)*4 + r];

        f32x4v yacc[4][4] = {};   // [mi][pi]
        u16* pw = &plds[wv][0];
        const float a_hi = acs[wv*64];

        for (int cb = wv; cb >= 0; --cb){
            if (a_hi - acs[cb*64 + 63] < -30.f) break;   // whole tile dead
#pragma unroll
            for (int mi = 0; mi < 4; mi++){
#pragma unroll
                for (int ni = 0; ni < 4; ni++){
                    f32x4v s4 = {};
#pragma unroll
                    for (int ks = 0; ks < 2; ks++){
                        short8b bfr = *(const short8b*)&brs[(cb*64 + ni*16 + fr)*72 + ks*32 + kb];
                        s4 = __builtin_amdgcn_mfma_f32_16x16x32_bf16(crf[mi][ks], bfr, s4, 0, 0, 0);
                    }
                    const int s_idx = cb*64 + ni*16 + fr;
                    const float a_s = acs[s_idx];
                    const int lrow0 = wv*64 + mi*16 + (lane >> 4)*4;
#pragma unroll
                    for (int r = 0; r < 4; r++){
                        float w  = __expf(fminf(al[mi][r] - a_s, 0.f));
                        float pv = (s_idx <= lrow0 + r) ? w * s4[r] : 0.f;
                        pw[(mi*16 + (lane >> 4)*4 + r)*72 + ni*16 + fr] = f2bf(pv);
                    }
                }
            }
            asm volatile("s_waitcnt lgkmcnt(0)" ::: "memory");
#pragma unroll
            for (int ks = 0; ks < 2; ks++){
                short8b paf[4];
#pragma unroll
                for (int mi = 0; mi < 4; mi++)
                    paf[mi] = *(const short8b*)&pw[(mi*16 + fr)*72 + ks*32 + kb];
#pragma unroll
                for (int pi = 0; pi < 4; pi++){
                    short8b xbf = *(const short8b*)&xdsT[(pi*16 + fr)*264 + cb*64 + ks*32 + kb];
#pragma unroll
                    for (int mi = 0; mi < 4; mi++)
                        yacc[mi][pi] = __builtin_amdgcn_mfma_f32_16x16x32_bf16(paf[mi], xbf, yacc[mi][pi], 0, 0, 0);
                }
            }
        }
#pragma unroll
        for (int mi = 0; mi < 4; mi++){
            const int lrow = wv*64 + mi*16 + (lane >> 4)*4;
#pragma unroll
            for (int r = 0; r < 4; r++){
                u16* yp = brY + (tokbase + lrow + r)*Dd + h*Pp + fr;
#pragma unroll
                for (int pi = 0; pi < 4; pi++)
                    yp[pi*16] = f2bf(yacc[mi][pi][r]);
            }
        }
    }
}

// ---------------------------------------------------------------------------
// Sequential inter-chunk scan IN PLACE: st[c] := h_prev; carry h.
// ---------------------------------------------------------------------------
template<int DT>
__global__ __launch_bounds__(256) void scan_kernel(
    float* st, const float* __restrict__ Acum, void* d_out, const int* __restrict__ flag)
{
    if (*flag != DT) return;
    const int g = blockIdx.x;
    const int seg = g & 15;
    const int bh = g >> 4;
    const int h = bh & 15, b = bh >> 4;
    const int e = seg*256 + threadIdx.x;
    const float* Ac = Acum + (size_t)(b*Hh + h)*NCc*CLc;
    float hst = 0.f;
    for (int c = 0; c < NCc; c++){
        float dec = __expf(fminf(Ac[c*CLc + 255], 0.f));
        size_t off = ((size_t)((b*NCc + c)*Hh) + h)*4096 + e;
        float s_val = st[off];
        st[off] = hst;
        hst = hst*dec + s_val;
    }
    size_t fi = (size_t)Mm*Dd + (size_t)(b*Hh + h)*4096 + e;
    if (DT) ((u16*)d_out)[fi] = f2bf(hst);
    else    ((float*)d_out)[fi] = hst;
}

// ---------------------------------------------------------------------------
// Y_off[l][p] = exp(a_l) * sum_n cr[l][n] * prev[p][n]; y += Y_off (ws bf16).
// ---------------------------------------------------------------------------
__global__ __launch_bounds__(256) void yoff_kernel(
    const u16* __restrict__ cr, const float* __restrict__ prev,
    const float* __restrict__ Acum, u16* y)
{
    __shared__ float ps[64*65];
    __shared__ u16 crs[256*64];
    const int g = blockIdx.x;
    const int h = g & 15, c = (g >> 4) & 31, b = g >> 9;
    const int t = threadIdx.x;
    const size_t tokbase = (size_t)b*Ll + (size_t)c*CLc;
    const float* pv = prev + ((size_t)((b*NCc + c)*Hh) + h)*4096;
#pragma unroll
    for (int i = 0; i < 16; i++){
        int f = i*256 + t;
        ps[(f >> 6)*65 + (f & 63)] = pv[f];
    }
#pragma unroll
    for (int i = 0; i < 16; i++){
        int f4 = i*256 + t;
        int l  = f4 >> 4;
        int n4 = (f4 & 15)*4;
        *(ushort4*)&crs[l*64 + n4] = *(const ushort4*)&cr[(tokbase + l)*Dd + h*Pp + n4];
    }
    __syncthreads();
    const int w = t >> 6, p = t & 63;
    float acc[64];
#pragma unroll
    for (int j=0;j<64;j++) acc[j]=0.f;
    for (int n = 0; n < 64; n++){
        float pvn = ps[p*65 + n];
#pragma unroll
        for (int j=0;j<64;j++)
            acc[j] += bf2f(crs[(w*64 + j)*64 + n]) * pvn;
    }
    const float* Ac = Acum + ((size_t)(b*Hh + h)*NCc + c)*CLc;
#pragma unroll
    for (int j=0;j<64;j++){
        int l = w*64 + j;
        float el = __expf(fminf(Ac[l], 0.f));
        size_t off = (tokbase + l)*Dd + h*Pp + p;
        y[off] = f2bf(bf2f(y[off]) + el*acc[j]);
    }
}

// ---------------------------------------------------------------------------
__global__ __launch_bounds__(256) void zero_out_kernel(void* o, long long n, const int* flag)
{
    long long i = (long long)blockIdx.x*256 + threadIdx.x;
    if (i < n){
        if (*flag) ((u16*)o)[i] = 0;
        else       ((float*)o)[i] = 0.f;
    }
}

// ---------------------------------------------------------------------------
extern "C" void kernel_launch(void* const* d_in, const int* in_sizes, int n_in,
                              void* d_out, int out_size, void* d_ws, size_t ws_size,
                              hipStream_t stream)
{
    const void* hs   = d_in[0];
    const void* cosb = d_in[1];
    const void* sinb = d_in[2];
    const void* Wc   = d_in[3];
    const void* Wb   = d_in[4];
    const void* Wdt  = d_in[5];
    const void* Wx   = d_in[6];
    const void* Wout = d_in[7];
    const void* Aarr = d_in[8];
    // d_in[9] = chunk_size (256, hardcoded)

    int*  flag  = (int*)d_ws;
    char* wbase = (char*)d_ws + 1024;

    const size_t NEED = 1024
                      + (size_t)3*Mm*Dd*2         // c, b(->y), x(->xdt) bf16
                      + (size_t)Mm*Hh*4           // dt fp32
                      + (size_t)Bb*Hh*Ll*4        // Acum fp32
                      + (size_t)Bb*NCc*Hh*4096*4  // states(->prev) fp32
                      + (size_t)Mm*Dd*2           // hs bf16
                      + (size_t)5*DD2*2;          // W^T bf16 x5

    sniff_kernel<<<1, 64, 0, stream>>>((const unsigned int*)cosb, flag);

    if (ws_size < NEED){
        long long n = (long long)out_size;
        zero_out_kernel<<<(unsigned)((n + 255)/256), 256, 0, stream>>>(d_out, n, flag);
        return;
    }

    u16*   c_buf  = (u16*)wbase;
    u16*   b_buf  = c_buf + (size_t)Mm*Dd;                 // br, then y in place
    u16*   x_buf  = b_buf + (size_t)Mm*Dd;                 // x, then xdt in place
    float* dt_buf = (float*)(x_buf + (size_t)Mm*Dd);
    float* acum   = dt_buf + (size_t)Mm*Hh;
    float* states = acum + (size_t)Bb*Hh*Ll;               // states, then prev
    u16*   hs_bf  = (u16*)(states + (size_t)Bb*NCc*Hh*4096);
    u16*   wt     = hs_bf + (size_t)Mm*Dd;                 // 5 transposed bf16 weights

    cvt_kernel<1><<<(Mm*Dd)/(256*8), 256, 0, stream>>>(hs, hs_bf, flag);
    cvt_kernel<0><<<(Mm*Dd)/(256*8), 256, 0, stream>>>(hs, hs_bf, flag);
    wtrans_kernel<1><<<dim3(16,16,4), 256, 0, stream>>>(Wc, Wb, Wx, Wout, wt, flag);
    wtrans_kernel<0><<<dim3(16,16,4), 256, 0, stream>>>(Wc, Wb, Wx, Wout, wt, flag);

    dt_kernel<1><<<Mm/16, 256, 0, stream>>>(hs, Wdt, dt_buf, flag);
    dt_kernel<0><<<Mm/16, 256, 0, stream>>>(hs, Wdt, dt_buf, flag);

    // fused projections: C spans c_buf|b_buf|x_buf (contiguous), Bt spans
    // Wc^T|Wb^T|Wx^T (contiguous in wt).  N=3072, grid 3072 blocks.
    gemm_mfma<1,0,1><<<(Mm/128)*(3072/128), 256, 0, stream>>>(
        hs_bf, wt, c_buf, Mm, 3072, Dd, flag, -1);

    rope_xdt_kernel<1><<<(Mm*Hh*32)/256, 256, 0, stream>>>(c_buf, b_buf, x_buf, dt_buf, cosb, sinb, flag);
    rope_xdt_kernel<0><<<(Mm*Hh*32)/256, 256, 0, stream>>>(c_buf, b_buf, x_buf, dt_buf, cosb, sinb, flag);
    cumsum_kernel<1><<<Bb*Hh*NCc, 256, 0, stream>>>(dt_buf, Aarr, acum, flag);
    cumsum_kernel<0><<<Bb*Hh*NCc, 256, 0, stream>>>(dt_buf, Aarr, acum, flag);
    chunk_kernel<<<Bb*NCc*Hh, 256, 0, stream>>>(c_buf, b_buf, x_buf, acum, states);
    scan_kernel<1><<<Bb*Hh*16, 256, 0, stream>>>(states, acum, d_out, flag);
    scan_kernel<0><<<Bb*Hh*16, 256, 0, stream>>>(states, acum, d_out, flag);
    yoff_kernel<<<Bb*NCc*Hh, 256, 0, stream>>>(c_buf, states, acum, b_buf);

    const int NWG = (Mm/128)*(Dd/128);   // 1024
    gemm_mfma<1,0,0><<<NWG, 256, 0, stream>>>(b_buf, wt + 3*DD2, d_out, Mm, Dd, Dd, flag, 1);
    gemm_mfma<0,0,0><<<NWG, 256, 0, stream>>>(b_buf, wt + 3*DD2, d_out, Mm, Dd, Dd, flag, 0);
    gemm_mfma<0,1,0><<<NWG, 256, 0, stream>>>(b_buf, wt + 4*DD2, d_out, Mm, Dd, Dd, flag, 0);
}